// Round 8
// baseline (868.483 us; speedup 1.0000x reference)
//
#include <hip/hip_runtime.h>

#define N_PTS 100000
#define NT_STRIDE 100096            // padded row count for nbrsT
#define NK 27
#define NKP 28                      // k slots incl. dummy zero slot k=27
#define TOTAL (N_PTS * 64)          // 6400000
#define NB_CONV 1564                // grid: 1564 blocks * 64 rows

typedef short bf16x8 __attribute__((ext_vector_type(8)));   // 8 bf16 in 4 VGPRs
typedef float f32x4 __attribute__((ext_vector_type(4)));
typedef unsigned short u16x8 __attribute__((ext_vector_type(8)));
typedef char i8x8 __attribute__((ext_vector_type(8)));      // 8 int8 in 2 VGPRs

__device__ __forceinline__ unsigned short f2bf(float f) {
    unsigned u = __builtin_bit_cast(unsigned, f);
    u += 0x7fffu + ((u >> 16) & 1u);           // round-to-nearest-even
    return (unsigned short)(u >> 16);
}
__device__ __forceinline__ float bf2f(unsigned short u) {
    return __builtin_bit_cast(float, ((unsigned)u) << 16);
}
// int8 row-slice -> bf16x8 with scale (round-half-up in bf16: bias <= ulp/2, irrelevant at int8 error scale)
__device__ __forceinline__ bf16x8 dq8(i8x8 q, float s) {
    u16x8 o;
#pragma unroll
    for (int j = 0; j < 8; ++j) {
        float f = (float)q[j] * s;
        unsigned u = __builtin_bit_cast(unsigned, f) + 0x8000u;
        o[j] = (unsigned short)(u >> 16);
    }
    return __builtin_bit_cast(bf16x8, o);
}

// ---------------- quantize feats -> int8 rows + per-row scale; zeroed pad row ----------------
__global__ void cast_in_k(const float* __restrict__ feats, char* __restrict__ xq,
                          float* __restrict__ stbl) {
    int t = blockIdx.x * 256 + threadIdx.x;
    if (t >= (N_PTS + 1) * 8) return;
    int i = t * 8;
    int row = t >> 3;
    if (row >= N_PTS) {                        // pad row
        *(i8x8*)(xq + i) = (i8x8)(char)0;
        if ((t & 7) == 0) stbl[row] = 0.f;
        return;
    }
    f32x4 v0 = ((const f32x4*)(feats + i))[0];
    f32x4 v1 = ((const f32x4*)(feats + i))[1];
    float m = 0.f;
#pragma unroll
    for (int j = 0; j < 4; ++j) m = fmaxf(m, fmaxf(fabsf(v0[j]), fabsf(v1[j])));
    m = fmaxf(m, __shfl_xor(m, 1));            // 8-thread (one row) max
    m = fmaxf(m, __shfl_xor(m, 2));
    m = fmaxf(m, __shfl_xor(m, 4));
    float inv = (m > 0.f) ? 127.0f / m : 0.f;
    i8x8 q;
#pragma unroll
    for (int j = 0; j < 4; ++j) {
        q[j]     = (char)(int)rintf(v0[j] * inv);
        q[4 + j] = (char)(int)rintf(v1[j] * inv);
    }
    *(i8x8*)(xq + i) = q;
    if ((t & 7) == 0) stbl[row] = m * (1.0f / 127.0f);
}

// ---------------- transpose rulebook: nbrsT[k][n] = nbrs[n][k]; k=27 row & pad rows -> N_PTS ----------------
__global__ void tr_nbrs_k(const int* __restrict__ nbrs, int* __restrict__ nbrsT) {
    __shared__ int tile[64 * 28];
    const int n0 = blockIdx.x * 64;
    const int t = threadIdx.x;
    const int base = n0 * 27;
    for (int i = t; i < 1728; i += 256) {
        int v = (base + i < N_PTS * 27) ? nbrs[base + i] : N_PTS;
        int r = i / 27, c = i - r * 27;
        tile[r * 28 + c] = v;
    }
    __syncthreads();
    for (int i = t; i < 1728; i += 256) {
        int k = i >> 6, j = i & 63;                        // k 0..26
        nbrsT[(size_t)k * NT_STRIDE + n0 + j] = tile[j * 28 + k];
    }
    for (int i = t; i < 64; i += 256)                      // dummy k=27 row -> pad
        nbrsT[(size_t)27 * NT_STRIDE + n0 + i] = N_PTS;
}

// ---------------- pack W -> bf16 MFMA-B-fragment order, 28 k-slots/conv (k=27 zeroed) ----------------
// Wp layout: [conv][k(28)][kk][cb][lane][8]; frag elem j is B[c = kk*32+(lane>>4)*8+j, d = cb*16+(lane&15)]
__global__ void pack_w_k(const float* __restrict__ W, unsigned short* __restrict__ Wp) {
    int o = blockIdx.x * 256 + threadIdx.x;
    if (o >= 4 * NKP * 4096) return;
    int conv = o / (NKP * 4096);
    int r = o - conv * (NKP * 4096);
    int k = r >> 12;
    if (k == 27) { Wp[o] = 0; return; }
    int r2 = r & 4095;
    int frag = r2 >> 9;
    int kk = frag >> 2, cb = frag & 3;
    int lane = (r2 >> 3) & 63;
    int j = r2 & 7;
    int c = kk * 32 + (lane >> 4) * 8 + j;
    int d = cb * 16 + (lane & 15);
    Wp[o] = f2bf(W[(size_t)(conv * NK + k) * 4096 + c * 64 + d]);
}

// ---------------- gather-GEMM conv: int8 table gather + in-register dequant, bf16 MFMA ----------------
// R5 structure (measured best): 4 waves = 2 rowhalves x 2 khalves (14 k-steps; kh=1 has zero dummy k=27),
// idx window 4, gather prefetch depth 2 (raw int8 + row scale), dequant at consume.
__global__ __launch_bounds__(256, 4) void conv_k(
    const char* __restrict__ xq,               // [N_PTS+1][64] int8
    const float* __restrict__ stbl,            // [N_PTS+1] row scales (L2-resident)
    const int* __restrict__ nbrsT,             // [28][NT_STRIDE]
    const unsigned short* __restrict__ Wp,     // packed bf16 fragments (28 k-slots)
    unsigned short* __restrict__ ybf,          // [N_PTS][64] bf16 raw conv output
    float* __restrict__ gpart_out)             // [128] accumulated sum/sumsq of output
{
    const int tid = threadIdx.x;
    const int lane = tid & 63;
    const int wave = tid >> 6;
    const int l15 = lane & 15;
    const int lgrp = lane >> 4;
    const int h = wave & 1;                    // rowhalf
    const int kh = wave >> 1;                  // khalf
    const int wave_row = blockIdx.x * 64 + h * 32;
    const int r0 = wave_row + l15;             // < NT_STRIDE always
    const int r1 = r0 + 16;
    const int k0 = kh * 14;

    f32x4 acc[2][4];
#pragma unroll
    for (int m = 0; m < 2; ++m)
#pragma unroll
        for (int cb = 0; cb < 4; ++cb) acc[m][cb] = (f32x4)0.f;

    const bf16x8* wp = (const bf16x8*)Wp;

    // idx pipeline: window of 4 per row-half
    int id0[4], id1[4];
#pragma unroll
    for (int s = 0; s < 4; ++s) {
        id0[s] = nbrsT[(size_t)(k0 + s) * NT_STRIDE + r0];
        id1[s] = nbrsT[(size_t)(k0 + s) * NT_STRIDE + r1];
    }
    // raw int8 prefetch: 3 stages x 4 slices ([0]=row0 ch0-31, [1]=row0 ch32-63, [2]=row1 ch0-31, [3]=row1 ch32-63)
    i8x8 qpf[3][4];
    float spf[3][2];
#pragma unroll
    for (int s = 0; s < 2; ++s) {
        const i8x8* p0 = (const i8x8*)(xq + (size_t)id0[s] * 64);
        const i8x8* p1 = (const i8x8*)(xq + (size_t)id1[s] * 64);
        qpf[s][0] = p0[lgrp]; qpf[s][1] = p0[4 + lgrp];
        qpf[s][2] = p1[lgrp]; qpf[s][3] = p1[4 + lgrp];
        spf[s][0] = stbl[id0[s]]; spf[s][1] = stbl[id1[s]];
    }

#pragma unroll
    for (int s = 0; s < 14; ++s) {
        if (s + 4 < 14) {                      // idx prefetch (coalesced)
            id0[s & 3] = nbrsT[(size_t)(k0 + s + 4) * NT_STRIDE + r0];
            id1[s & 3] = nbrsT[(size_t)(k0 + s + 4) * NT_STRIDE + r1];
        }
        if (s + 2 < 14) {                      // gather prefetch for s+2 (raw int8 + scales)
            const int j = (s + 2) & 3;
            const int st2 = (s + 2) % 3;
            const i8x8* p0 = (const i8x8*)(xq + (size_t)id0[j] * 64);
            const i8x8* p1 = (const i8x8*)(xq + (size_t)id1[j] * 64);
            qpf[st2][0] = p0[lgrp]; qpf[st2][1] = p0[4 + lgrp];
            qpf[st2][2] = p1[lgrp]; qpf[st2][3] = p1[4 + lgrp];
            spf[st2][0] = stbl[id0[j]]; spf[st2][1] = stbl[id1[j]];
        }
        __builtin_amdgcn_sched_barrier(0);     // keep prefetch issue ahead of consume
        const int st = s % 3;
        bf16x8 a00 = dq8(qpf[st][0], spf[st][0]);
        bf16x8 a01 = dq8(qpf[st][1], spf[st][0]);
        bf16x8 a10 = dq8(qpf[st][2], spf[st][1]);
        bf16x8 a11 = dq8(qpf[st][3], spf[st][1]);
        const bf16x8* wk = wp + (size_t)(k0 + s) * 512 + lane;
        {   // kk = 0 (c 0..31)
            bf16x8 b0 = wk[0], b1 = wk[64], b2 = wk[128], b3 = wk[192];
            acc[0][0] = __builtin_amdgcn_mfma_f32_16x16x32_bf16(a00, b0, acc[0][0], 0, 0, 0);
            acc[1][0] = __builtin_amdgcn_mfma_f32_16x16x32_bf16(a10, b0, acc[1][0], 0, 0, 0);
            acc[0][1] = __builtin_amdgcn_mfma_f32_16x16x32_bf16(a00, b1, acc[0][1], 0, 0, 0);
            acc[1][1] = __builtin_amdgcn_mfma_f32_16x16x32_bf16(a10, b1, acc[1][1], 0, 0, 0);
            acc[0][2] = __builtin_amdgcn_mfma_f32_16x16x32_bf16(a00, b2, acc[0][2], 0, 0, 0);
            acc[1][2] = __builtin_amdgcn_mfma_f32_16x16x32_bf16(a10, b2, acc[1][2], 0, 0, 0);
            acc[0][3] = __builtin_amdgcn_mfma_f32_16x16x32_bf16(a00, b3, acc[0][3], 0, 0, 0);
            acc[1][3] = __builtin_amdgcn_mfma_f32_16x16x32_bf16(a10, b3, acc[1][3], 0, 0, 0);
        }
        {   // kk = 1 (c 32..63)
            bf16x8 b0 = wk[256], b1 = wk[320], b2 = wk[384], b3 = wk[448];
            acc[0][0] = __builtin_amdgcn_mfma_f32_16x16x32_bf16(a01, b0, acc[0][0], 0, 0, 0);
            acc[1][0] = __builtin_amdgcn_mfma_f32_16x16x32_bf16(a11, b0, acc[1][0], 0, 0, 0);
            acc[0][1] = __builtin_amdgcn_mfma_f32_16x16x32_bf16(a01, b1, acc[0][1], 0, 0, 0);
            acc[1][1] = __builtin_amdgcn_mfma_f32_16x16x32_bf16(a11, b1, acc[1][1], 0, 0, 0);
            acc[0][2] = __builtin_amdgcn_mfma_f32_16x16x32_bf16(a01, b2, acc[0][2], 0, 0, 0);
            acc[1][2] = __builtin_amdgcn_mfma_f32_16x16x32_bf16(a11, b2, acc[1][2], 0, 0, 0);
            acc[0][3] = __builtin_amdgcn_mfma_f32_16x16x32_bf16(a01, b3, acc[0][3], 0, 0, 0);
            acc[1][3] = __builtin_amdgcn_mfma_f32_16x16x32_bf16(a11, b3, acc[1][3], 0, 0, 0);
        }
    }

    // ---- K-half reduction through LDS f32 tile (row stride 68 keeps 16B alignment) ----
    __shared__ __align__(16) float ytile[64 * 68];
    __shared__ __align__(16) float sred[4][128];

    if (kh == 0) {
#pragma unroll
        for (int m = 0; m < 2; ++m)
#pragma unroll
            for (int cb = 0; cb < 4; ++cb)
#pragma unroll
                for (int r = 0; r < 4; ++r)
                    ytile[(h * 32 + m * 16 + lgrp * 4 + r) * 68 + cb * 16 + l15] = acc[m][cb][r];
    }
    __syncthreads();
    if (kh == 1) {
#pragma unroll
        for (int m = 0; m < 2; ++m)
#pragma unroll
            for (int cb = 0; cb < 4; ++cb)
#pragma unroll
                for (int r = 0; r < 4; ++r)
                    ytile[(h * 32 + m * 16 + lgrp * 4 + r) * 68 + cb * 16 + l15] += acc[m][cb][r];
    }
    __syncthreads();

    // ---- coalesced read-out -> bf16 y store + per-channel sum/sumsq ----
    const int row = tid >> 2;                  // 0..63
    const int colb = (tid & 3) * 16;           // 0,16,32,48
    f32x4 v[4];
#pragma unroll
    for (int j = 0; j < 4; ++j) v[j] = *(const f32x4*)&ytile[row * 68 + colb + 4 * j];

    const int grow = blockIdx.x * 64 + row;
    if (grow < N_PTS) {
        u16x8 o0, o1;
#pragma unroll
        for (int j = 0; j < 4; ++j) { o0[j] = f2bf(v[0][j]); o0[4 + j] = f2bf(v[1][j]); }
#pragma unroll
        for (int j = 0; j < 4; ++j) { o1[j] = f2bf(v[2][j]); o1[4 + j] = f2bf(v[3][j]); }
        *(u16x8*)(ybf + (size_t)grow * 64 + colb) = o0;
        *(u16x8*)(ybf + (size_t)grow * 64 + colb + 8) = o1;
    }

    f32x4 sv[4], s2v[4];
#pragma unroll
    for (int j = 0; j < 4; ++j) { sv[j] = v[j]; s2v[j] = v[j] * v[j]; }
#pragma unroll
    for (int off = 4; off < 64; off <<= 1) {
#pragma unroll
        for (int j = 0; j < 4; ++j) {
#pragma unroll
            for (int e = 0; e < 4; ++e) {
                sv[j][e]  += __shfl_xor(sv[j][e],  off);
                s2v[j][e] += __shfl_xor(s2v[j][e], off);
            }
        }
    }
    if (lane < 4) {
#pragma unroll
        for (int j = 0; j < 4; ++j) {
            *(f32x4*)&sred[wave][lane * 16 + 4 * j]      = sv[j];
            *(f32x4*)&sred[wave][64 + lane * 16 + 4 * j] = s2v[j];
        }
    }
    __syncthreads();
    if (tid < 128) {
        float p = sred[0][tid] + sred[1][tid] + sred[2][tid] + sred[3][tid];
        atomicAdd(&gpart_out[tid], p);
    }
}

// ---------------- BN(inline stats) + ReLU -> int8 rows + scales (input to next conv) ----------------
__global__ void bn_relu_quant_k(const unsigned short* __restrict__ yraw,
                                const float* __restrict__ gpart,
                                const float* __restrict__ gamma,
                                const float* __restrict__ beta,
                                char* __restrict__ xq, float* __restrict__ stbl) {
    int t = blockIdx.x * 256 + threadIdx.x;
    if (t >= (N_PTS + 1) * 8) return;
    int i = t * 8;
    int row = t >> 3;
    if (row >= N_PTS) {                        // pad row
        *(i8x8*)(xq + i) = (i8x8)(char)0;
        if ((t & 7) == 0) stbl[row] = 0.f;
        return;
    }
    int c0 = i & 63;
    u16x8 v = *(const u16x8*)(yraw + i);
    const float invN = 1.0f / (float)N_PTS;
    float ov[8];
    float m = 0.f;
#pragma unroll
    for (int j = 0; j < 8; ++j) {
        int c = c0 + j;
        float S = gpart[c], S2 = gpart[64 + c];
        float mu = S * invN;
        float var = S2 * invN - mu * mu;
        float s = gamma[c] * rsqrtf(var + 1e-4f);
        ov[j] = fmaxf(bf2f(v[j]) * s + (beta[c] - mu * s), 0.f);
        m = fmaxf(m, ov[j]);
    }
    m = fmaxf(m, __shfl_xor(m, 1));
    m = fmaxf(m, __shfl_xor(m, 2));
    m = fmaxf(m, __shfl_xor(m, 4));
    float inv = (m > 0.f) ? 127.0f / m : 0.f;
    i8x8 q;
#pragma unroll
    for (int j = 0; j < 8; ++j) q[j] = (char)(int)rintf(ov[j] * inv);
    *(i8x8*)(xq + i) = q;
    if ((t & 7) == 0) stbl[row] = m * (1.0f / 127.0f);
}

// ---------------- blk0: BN + f32 residual + ReLU -> int8 rows + scales (doubles as blk1 residual) ----------------
__global__ void bn_add_relu_quant_k(const unsigned short* __restrict__ yraw,
                                    const float* __restrict__ gpart,
                                    const float* __restrict__ gamma,
                                    const float* __restrict__ beta,
                                    const float* __restrict__ res,
                                    char* __restrict__ xq, float* __restrict__ stbl) {
    int t = blockIdx.x * 256 + threadIdx.x;
    if (t >= TOTAL / 8) return;                // pad row of xq preserved from cast_in_k (zeros)
    int i = t * 8;
    int row = t >> 3;
    int c0 = i & 63;
    u16x8 v = *(const u16x8*)(yraw + i);
    f32x4 q0 = ((const f32x4*)(res + i))[0];
    f32x4 q1 = ((const f32x4*)(res + i))[1];
    const float invN = 1.0f / (float)N_PTS;
    float ov[8];
    float m = 0.f;
#pragma unroll
    for (int j = 0; j < 8; ++j) {
        int c = c0 + j;
        float S = gpart[c], S2 = gpart[64 + c];
        float mu = S * invN;
        float var = S2 * invN - mu * mu;
        float s = gamma[c] * rsqrtf(var + 1e-4f);
        float r = (j < 4) ? q0[j] : q1[j - 4];
        ov[j] = fmaxf(bf2f(v[j]) * s + (beta[c] - mu * s) + r, 0.f);
        m = fmaxf(m, ov[j]);
    }
    m = fmaxf(m, __shfl_xor(m, 1));
    m = fmaxf(m, __shfl_xor(m, 2));
    m = fmaxf(m, __shfl_xor(m, 4));
    float inv = (m > 0.f) ? 127.0f / m : 0.f;
    i8x8 q;
#pragma unroll
    for (int j = 0; j < 8; ++j) q[j] = (char)(int)rintf(ov[j] * inv);
    *(i8x8*)(xq + i) = q;
    if ((t & 7) == 0) stbl[row] = m * (1.0f / 127.0f);
}

// ---------------- blk1: BN + int8-dequant residual + ReLU -> final f32 out ----------------
__global__ void bn_add_relu_final_k(const unsigned short* __restrict__ yraw,
                                    const float* __restrict__ gpart,
                                    const float* __restrict__ gamma,
                                    const float* __restrict__ beta,
                                    const char* __restrict__ resq,
                                    const float* __restrict__ res_stbl,
                                    float* __restrict__ xout) {
    int t = blockIdx.x * 256 + threadIdx.x;
    if (t >= TOTAL / 8) return;
    int i = t * 8;
    int row = t >> 3;
    int c0 = i & 63;
    u16x8 v = *(const u16x8*)(yraw + i);
    i8x8 rq = *(const i8x8*)(resq + i);
    float rs = res_stbl[row];
    const float invN = 1.0f / (float)N_PTS;
    f32x4 o0, o1;
#pragma unroll
    for (int j = 0; j < 8; ++j) {
        int c = c0 + j;
        float S = gpart[c], S2 = gpart[64 + c];
        float mu = S * invN;
        float var = S2 * invN - mu * mu;
        float s = gamma[c] * rsqrtf(var + 1e-4f);
        float r = (float)rq[j] * rs;
        float o = fmaxf(bf2f(v[j]) * s + (beta[c] - mu * s) + r, 0.f);
        if (j < 4) o0[j] = o; else o1[j - 4] = o;
    }
    ((f32x4*)(xout + i))[0] = o0;
    ((f32x4*)(xout + i))[1] = o1;
}

extern "C" void kernel_launch(void* const* d_in, const int* in_sizes, int n_in,
                              void* d_out, int out_size, void* d_ws, size_t ws_size,
                              hipStream_t stream) {
    const float* feats = (const float*)d_in[0];
    const int*   nbrs  = (const int*)d_in[1];
    const float* W     = (const float*)d_in[2];
    const float* gamma = (const float*)d_in[3];
    const float* beta  = (const float*)d_in[4];
    float* out = (float*)d_out;

    char* ws = (char*)d_ws;
    char*           xq0   = ws;                               //  6,400,128 B (incl pad row)
    float*          stbl0 = (float*)(ws + 6400128);           //    400,016 B
    char*           xq1   = ws + 6800144;                     //  6,400,128 B
    float*          stbl1 = (float*)(ws + 13200272);          //    400,016 B
    unsigned short* ybf   = (unsigned short*)(ws + 13600288); // 12,800,000 B
    unsigned short* Wp    = (unsigned short*)(ws + 26400288); //    917,504 B
    int*            nbrsT = (int*)(ws + 27317792);            // 11,210,752 B
    float*          gpart = (float*)(ws + 38528544);          //      2,048 B (4 slots x 128)

    dim3 b256(256);
    hipMemsetAsync(gpart, 0, 4 * 128 * sizeof(float), stream);
    const int qrows_blocks = ((N_PTS + 1) * 8 + 255) / 256;   // 3126
    cast_in_k<<<qrows_blocks, b256, 0, stream>>>(feats, xq0, stbl0);
    tr_nbrs_k<<<NT_STRIDE / 64, b256, 0, stream>>>(nbrs, nbrsT);
    pack_w_k<<<(4 * NKP * 4096) / 256, b256, 0, stream>>>(W, Wp);

    const int appl_blocks = (TOTAL / 8 + 255) / 256;          // 3125
    for (int blk = 0; blk < 2; ++blk) {
        const int c0 = blk * 2, c1 = blk * 2 + 1;
        // conv c0: xq0 -> ybf, stats -> slot c0
        conv_k<<<NB_CONV, b256, 0, stream>>>(
            xq0, stbl0, nbrsT, Wp + (size_t)c0 * NKP * 4096, ybf, gpart + c0 * 128);
        // bn(c0)+relu -> int8 xq1
        bn_relu_quant_k<<<qrows_blocks, b256, 0, stream>>>(
            ybf, gpart + c0 * 128, gamma + c0 * 64, beta + c0 * 64, xq1, stbl1);
        // conv c1: xq1 -> ybf, stats -> slot c1
        conv_k<<<NB_CONV, b256, 0, stream>>>(
            xq1, stbl1, nbrsT, Wp + (size_t)c1 * NKP * 4096, ybf, gpart + c1 * 128);
        if (blk == 0) {
            // bn(c1) + feats residual + relu -> int8 xq0 (conv3 input AND blk1 residual)
            bn_add_relu_quant_k<<<appl_blocks, b256, 0, stream>>>(
                ybf, gpart + c1 * 128, gamma + c1 * 64, beta + c1 * 64, feats, xq0, stbl0);
        } else {
            // bn(c1) + dequant(xq0) residual + relu -> final f32 out
            bn_add_relu_final_k<<<appl_blocks, b256, 0, stream>>>(
                ybf, gpart + c1 * 128, gamma + c1 * 64, beta + c1 * 64, xq0, stbl0, out);
        }
    }
}

// Round 9
// 857.383 us; speedup vs baseline: 1.0129x; 1.0129x over previous
//
#include <hip/hip_runtime.h>

#define N_PTS 100000
#define NT_STRIDE 100096            // padded row count for nbrsT
#define NK 27
#define NKP 28                      // k slots incl. dummy zero slot k=27
#define TOTAL (N_PTS * 64)          // 6400000
#define NB_CONV 1564                // grid: 1564 blocks * 64 rows

typedef short bf16x8 __attribute__((ext_vector_type(8)));   // 8 bf16 in 4 VGPRs
typedef float f32x4 __attribute__((ext_vector_type(4)));
typedef unsigned short u16x8 __attribute__((ext_vector_type(8)));
typedef char i8x8 __attribute__((ext_vector_type(8)));      // 8 int8 in 2 VGPRs

__device__ __forceinline__ unsigned short f2bf(float f) {
    unsigned u = __builtin_bit_cast(unsigned, f);
    u += 0x7fffu + ((u >> 16) & 1u);           // round-to-nearest-even
    return (unsigned short)(u >> 16);
}
__device__ __forceinline__ float bf2f(unsigned short u) {
    return __builtin_bit_cast(float, ((unsigned)u) << 16);
}
// int8 row-slice -> bf16x8 with scale (round-half-up in bf16: bias <= ulp/2, tiny vs int8 error)
__device__ __forceinline__ bf16x8 dq8(i8x8 q, float s) {
    u16x8 o;
#pragma unroll
    for (int j = 0; j < 8; ++j) {
        float f = (float)q[j] * s;
        unsigned u = __builtin_bit_cast(unsigned, f) + 0x8000u;
        o[j] = (unsigned short)(u >> 16);
    }
    return __builtin_bit_cast(bf16x8, o);
}

// ---------------- quantize feats -> int8 rows + per-row scale; zeroed pad row ----------------
__global__ void cast_in_k(const float* __restrict__ feats, char* __restrict__ xq,
                          float* __restrict__ stbl) {
    int t = blockIdx.x * 256 + threadIdx.x;
    if (t >= (N_PTS + 1) * 8) return;
    int i = t * 8;
    int row = t >> 3;
    if (row >= N_PTS) {                        // pad row
        *(i8x8*)(xq + i) = (i8x8)(char)0;
        if ((t & 7) == 0) stbl[row] = 0.f;
        return;
    }
    f32x4 v0 = ((const f32x4*)(feats + i))[0];
    f32x4 v1 = ((const f32x4*)(feats + i))[1];
    float m = 0.f;
#pragma unroll
    for (int j = 0; j < 4; ++j) m = fmaxf(m, fmaxf(fabsf(v0[j]), fabsf(v1[j])));
    m = fmaxf(m, __shfl_xor(m, 1));            // 8-thread (one row) max
    m = fmaxf(m, __shfl_xor(m, 2));
    m = fmaxf(m, __shfl_xor(m, 4));
    float inv = (m > 0.f) ? 127.0f / m : 0.f;
    i8x8 q;
#pragma unroll
    for (int j = 0; j < 4; ++j) {
        q[j]     = (char)(int)rintf(v0[j] * inv);
        q[4 + j] = (char)(int)rintf(v1[j] * inv);
    }
    *(i8x8*)(xq + i) = q;
    if ((t & 7) == 0) stbl[row] = m * (1.0f / 127.0f);
}

// ---------------- transpose rulebook: nbrsT[k][n] = nbrs[n][k]; k=27 row & pad rows -> N_PTS ----------------
__global__ void tr_nbrs_k(const int* __restrict__ nbrs, int* __restrict__ nbrsT) {
    __shared__ int tile[64 * 28];
    const int n0 = blockIdx.x * 64;
    const int t = threadIdx.x;
    const int base = n0 * 27;
    for (int i = t; i < 1728; i += 256) {
        int v = (base + i < N_PTS * 27) ? nbrs[base + i] : N_PTS;
        int r = i / 27, c = i - r * 27;
        tile[r * 28 + c] = v;
    }
    __syncthreads();
    for (int i = t; i < 1728; i += 256) {
        int k = i >> 6, j = i & 63;                        // k 0..26
        nbrsT[(size_t)k * NT_STRIDE + n0 + j] = tile[j * 28 + k];
    }
    for (int i = t; i < 64; i += 256)                      // dummy k=27 row -> pad
        nbrsT[(size_t)27 * NT_STRIDE + n0 + i] = N_PTS;
}

// ---------------- pack W -> bf16 MFMA-B-fragment order, 28 k-slots/conv (k=27 zeroed) ----------------
// Wp layout: [conv][k(28)][kk][cb][lane][8]; frag elem j is B[c = kk*32+(lane>>4)*8+j, d = cb*16+(lane&15)]
__global__ void pack_w_k(const float* __restrict__ W, unsigned short* __restrict__ Wp) {
    int o = blockIdx.x * 256 + threadIdx.x;
    if (o >= 4 * NKP * 4096) return;
    int conv = o / (NKP * 4096);
    int r = o - conv * (NKP * 4096);
    int k = r >> 12;
    if (k == 27) { Wp[o] = 0; return; }
    int r2 = r & 4095;
    int frag = r2 >> 9;
    int kk = frag >> 2, cb = frag & 3;
    int lane = (r2 >> 3) & 63;
    int j = r2 & 7;
    int c = kk * 32 + (lane >> 4) * 8 + j;
    int d = cb * 16 + (lane & 15);
    Wp[o] = f2bf(W[(size_t)(conv * NK + k) * 4096 + c * 64 + d]);
}

// ---------------- gather-GEMM conv: int8 gather + in-register dequant, bf16 MFMA ----------------
// R5 pipeline structure (measured best) but with NAMED ping-pong registers (rule #20:
// no runtime-indexed register arrays -> no scratch, regardless of unrolling).
// Per step: consume buffer (dequant) -> re-gather into same named buffer (k+2) -> refill idx (k+4) -> MFMA.
#define STEP(scur, Q, I)                                                              \
    {                                                                                 \
        bf16x8 a00 = dq8(Q##0, Q##s0);                                                \
        bf16x8 a01 = dq8(Q##1, Q##s0);                                                \
        bf16x8 a10 = dq8(Q##2, Q##s1);                                                \
        bf16x8 a11 = dq8(Q##3, Q##s1);                                                \
        if ((scur) + 2 < 14) {                                                        \
            const i8x8* p0 = (const i8x8*)(xq + (size_t)I##0 * 64);                   \
            const i8x8* p1 = (const i8x8*)(xq + (size_t)I##1 * 64);                   \
            Q##0 = p0[lgrp]; Q##1 = p0[4 + lgrp];                                     \
            Q##2 = p1[lgrp]; Q##3 = p1[4 + lgrp];                                     \
            Q##s0 = stbl[I##0]; Q##s1 = stbl[I##1];                                   \
        }                                                                             \
        if ((scur) + 4 < 14) {                                                        \
            I##0 = nbrsT[(size_t)(k0 + (scur) + 4) * NT_STRIDE + r0];                 \
            I##1 = nbrsT[(size_t)(k0 + (scur) + 4) * NT_STRIDE + r1];                 \
        }                                                                             \
        __builtin_amdgcn_sched_barrier(0);                                            \
        const bf16x8* wk = wp + (size_t)(k0 + (scur)) * 512 + lane;                   \
        {   /* kk = 0 (c 0..31) */                                                    \
            bf16x8 b0 = wk[0], b1 = wk[64], b2 = wk[128], b3 = wk[192];               \
            acc[0][0] = __builtin_amdgcn_mfma_f32_16x16x32_bf16(a00, b0, acc[0][0], 0, 0, 0); \
            acc[1][0] = __builtin_amdgcn_mfma_f32_16x16x32_bf16(a10, b0, acc[1][0], 0, 0, 0); \
            acc[0][1] = __builtin_amdgcn_mfma_f32_16x16x32_bf16(a00, b1, acc[0][1], 0, 0, 0); \
            acc[1][1] = __builtin_amdgcn_mfma_f32_16x16x32_bf16(a10, b1, acc[1][1], 0, 0, 0); \
            acc[0][2] = __builtin_amdgcn_mfma_f32_16x16x32_bf16(a00, b2, acc[0][2], 0, 0, 0); \
            acc[1][2] = __builtin_amdgcn_mfma_f32_16x16x32_bf16(a10, b2, acc[1][2], 0, 0, 0); \
            acc[0][3] = __builtin_amdgcn_mfma_f32_16x16x32_bf16(a00, b3, acc[0][3], 0, 0, 0); \
            acc[1][3] = __builtin_amdgcn_mfma_f32_16x16x32_bf16(a10, b3, acc[1][3], 0, 0, 0); \
        }                                                                             \
        {   /* kk = 1 (c 32..63) */                                                   \
            bf16x8 b0 = wk[256], b1 = wk[320], b2 = wk[384], b3 = wk[448];            \
            acc[0][0] = __builtin_amdgcn_mfma_f32_16x16x32_bf16(a01, b0, acc[0][0], 0, 0, 0); \
            acc[1][0] = __builtin_amdgcn_mfma_f32_16x16x32_bf16(a11, b0, acc[1][0], 0, 0, 0); \
            acc[0][1] = __builtin_amdgcn_mfma_f32_16x16x32_bf16(a01, b1, acc[0][1], 0, 0, 0); \
            acc[1][1] = __builtin_amdgcn_mfma_f32_16x16x32_bf16(a11, b1, acc[1][1], 0, 0, 0); \
            acc[0][2] = __builtin_amdgcn_mfma_f32_16x16x32_bf16(a01, b2, acc[0][2], 0, 0, 0); \
            acc[1][2] = __builtin_amdgcn_mfma_f32_16x16x32_bf16(a11, b2, acc[1][2], 0, 0, 0); \
            acc[0][3] = __builtin_amdgcn_mfma_f32_16x16x32_bf16(a01, b3, acc[0][3], 0, 0, 0); \
            acc[1][3] = __builtin_amdgcn_mfma_f32_16x16x32_bf16(a11, b3, acc[1][3], 0, 0, 0); \
        }                                                                             \
    }

__global__ __launch_bounds__(256, 4) void conv_k(
    const char* __restrict__ xq,               // [N_PTS+1][64] int8
    const float* __restrict__ stbl,            // [N_PTS+1] row scales (L2-resident)
    const int* __restrict__ nbrsT,             // [28][NT_STRIDE]
    const unsigned short* __restrict__ Wp,     // packed bf16 fragments (28 k-slots)
    unsigned short* __restrict__ ybf,          // [N_PTS][64] bf16 raw conv output
    float* __restrict__ gpart_out)             // [128] accumulated sum/sumsq of output
{
    const int tid = threadIdx.x;
    const int lane = tid & 63;
    const int wave = tid >> 6;
    const int l15 = lane & 15;
    const int lgrp = lane >> 4;
    const int h = wave & 1;                    // rowhalf
    const int kh = wave >> 1;                  // khalf
    const int wave_row = blockIdx.x * 64 + h * 32;
    const int r0 = wave_row + l15;             // < NT_STRIDE always
    const int r1 = r0 + 16;
    const int k0 = kh * 14;                    // kh=0: k 0..13 ; kh=1: k 14..27 (27 = zeros)

    f32x4 acc[2][4];
#pragma unroll
    for (int m = 0; m < 2; ++m)
#pragma unroll
        for (int cb = 0; cb < 4; ++cb) acc[m][cb] = (f32x4)0.f;

    const bf16x8* wp = (const bf16x8*)Wp;

    // ---- prologue: idx 2 ahead, gather 2 ahead; all NAMED registers ----
    int iE0 = nbrsT[(size_t)(k0 + 0) * NT_STRIDE + r0];
    int iE1 = nbrsT[(size_t)(k0 + 0) * NT_STRIDE + r1];
    int iO0 = nbrsT[(size_t)(k0 + 1) * NT_STRIDE + r0];
    int iO1 = nbrsT[(size_t)(k0 + 1) * NT_STRIDE + r1];
    i8x8 qE0, qE1, qE2, qE3, qO0, qO1, qO2, qO3;
    float qEs0, qEs1, qOs0, qOs1;
    {
        const i8x8* p0 = (const i8x8*)(xq + (size_t)iE0 * 64);
        const i8x8* p1 = (const i8x8*)(xq + (size_t)iE1 * 64);
        qE0 = p0[lgrp]; qE1 = p0[4 + lgrp]; qE2 = p1[lgrp]; qE3 = p1[4 + lgrp];
        qEs0 = stbl[iE0]; qEs1 = stbl[iE1];
    }
    iE0 = nbrsT[(size_t)(k0 + 2) * NT_STRIDE + r0];
    iE1 = nbrsT[(size_t)(k0 + 2) * NT_STRIDE + r1];
    {
        const i8x8* p0 = (const i8x8*)(xq + (size_t)iO0 * 64);
        const i8x8* p1 = (const i8x8*)(xq + (size_t)iO1 * 64);
        qO0 = p0[lgrp]; qO1 = p0[4 + lgrp]; qO2 = p1[lgrp]; qO3 = p1[4 + lgrp];
        qOs0 = stbl[iO0]; qOs1 = stbl[iO1];
    }
    iO0 = nbrsT[(size_t)(k0 + 3) * NT_STRIDE + r0];
    iO1 = nbrsT[(size_t)(k0 + 3) * NT_STRIDE + r1];

#pragma unroll
    for (int ss = 0; ss < 7; ++ss) {
        STEP(2 * ss,     qE, iE);
        STEP(2 * ss + 1, qO, iO);
    }

    // ---- K-half reduction through LDS f32 tile (row stride 68 keeps 16B alignment) ----
    __shared__ __align__(16) float ytile[64 * 68];
    __shared__ __align__(16) float sred[4][128];

    if (kh == 0) {
#pragma unroll
        for (int m = 0; m < 2; ++m)
#pragma unroll
            for (int cb = 0; cb < 4; ++cb)
#pragma unroll
                for (int r = 0; r < 4; ++r)
                    ytile[(h * 32 + m * 16 + lgrp * 4 + r) * 68 + cb * 16 + l15] = acc[m][cb][r];
    }
    __syncthreads();
    if (kh == 1) {
#pragma unroll
        for (int m = 0; m < 2; ++m)
#pragma unroll
            for (int cb = 0; cb < 4; ++cb)
#pragma unroll
                for (int r = 0; r < 4; ++r)
                    ytile[(h * 32 + m * 16 + lgrp * 4 + r) * 68 + cb * 16 + l15] += acc[m][cb][r];
    }
    __syncthreads();

    // ---- coalesced read-out -> bf16 y store + per-channel sum/sumsq ----
    const int row = tid >> 2;                  // 0..63
    const int colb = (tid & 3) * 16;           // 0,16,32,48
    f32x4 v[4];
#pragma unroll
    for (int j = 0; j < 4; ++j) v[j] = *(const f32x4*)&ytile[row * 68 + colb + 4 * j];

    const int grow = blockIdx.x * 64 + row;
    if (grow < N_PTS) {
        u16x8 o0, o1;
#pragma unroll
        for (int j = 0; j < 4; ++j) { o0[j] = f2bf(v[0][j]); o0[4 + j] = f2bf(v[1][j]); }
#pragma unroll
        for (int j = 0; j < 4; ++j) { o1[j] = f2bf(v[2][j]); o1[4 + j] = f2bf(v[3][j]); }
        *(u16x8*)(ybf + (size_t)grow * 64 + colb) = o0;
        *(u16x8*)(ybf + (size_t)grow * 64 + colb + 8) = o1;
    }

    f32x4 sv[4], s2v[4];
#pragma unroll
    for (int j = 0; j < 4; ++j) { sv[j] = v[j]; s2v[j] = v[j] * v[j]; }
#pragma unroll
    for (int off = 4; off < 64; off <<= 1) {
#pragma unroll
        for (int j = 0; j < 4; ++j) {
#pragma unroll
            for (int e = 0; e < 4; ++e) {
                sv[j][e]  += __shfl_xor(sv[j][e],  off);
                s2v[j][e] += __shfl_xor(s2v[j][e], off);
            }
        }
    }
    if (lane < 4) {
#pragma unroll
        for (int j = 0; j < 4; ++j) {
            *(f32x4*)&sred[wave][lane * 16 + 4 * j]      = sv[j];
            *(f32x4*)&sred[wave][64 + lane * 16 + 4 * j] = s2v[j];
        }
    }
    __syncthreads();
    if (tid < 128) {
        float p = sred[0][tid] + sred[1][tid] + sred[2][tid] + sred[3][tid];
        atomicAdd(&gpart_out[tid], p);
    }
}

// ---------------- BN(inline stats) + ReLU -> int8 rows + scales (input to next conv) ----------------
__global__ void bn_relu_quant_k(const unsigned short* __restrict__ yraw,
                                const float* __restrict__ gpart,
                                const float* __restrict__ gamma,
                                const float* __restrict__ beta,
                                char* __restrict__ xq, float* __restrict__ stbl) {
    int t = blockIdx.x * 256 + threadIdx.x;
    if (t >= (N_PTS + 1) * 8) return;
    int i = t * 8;
    int row = t >> 3;
    if (row >= N_PTS) {                        // pad row
        *(i8x8*)(xq + i) = (i8x8)(char)0;
        if ((t & 7) == 0) stbl[row] = 0.f;
        return;
    }
    int c0 = i & 63;
    u16x8 v = *(const u16x8*)(yraw + i);
    const float invN = 1.0f / (float)N_PTS;
    float ov[8];
    float m = 0.f;
#pragma unroll
    for (int j = 0; j < 8; ++j) {
        int c = c0 + j;
        float S = gpart[c], S2 = gpart[64 + c];
        float mu = S * invN;
        float var = S2 * invN - mu * mu;
        float s = gamma[c] * rsqrtf(var + 1e-4f);
        ov[j] = fmaxf(bf2f(v[j]) * s + (beta[c] - mu * s), 0.f);
        m = fmaxf(m, ov[j]);
    }
    m = fmaxf(m, __shfl_xor(m, 1));
    m = fmaxf(m, __shfl_xor(m, 2));
    m = fmaxf(m, __shfl_xor(m, 4));
    float inv = (m > 0.f) ? 127.0f / m : 0.f;
    i8x8 q;
#pragma unroll
    for (int j = 0; j < 8; ++j) q[j] = (char)(int)rintf(ov[j] * inv);
    *(i8x8*)(xq + i) = q;
    if ((t & 7) == 0) stbl[row] = m * (1.0f / 127.0f);
}

// ---------------- blk0: BN + f32 residual + ReLU -> int8 rows + scales (doubles as blk1 residual) ----------------
__global__ void bn_add_relu_quant_k(const unsigned short* __restrict__ yraw,
                                    const float* __restrict__ gpart,
                                    const float* __restrict__ gamma,
                                    const float* __restrict__ beta,
                                    const float* __restrict__ res,
                                    char* __restrict__ xq, float* __restrict__ stbl) {
    int t = blockIdx.x * 256 + threadIdx.x;
    if (t >= TOTAL / 8) return;                // pad row of xq preserved from cast_in_k (zeros)
    int i = t * 8;
    int row = t >> 3;
    int c0 = i & 63;
    u16x8 v = *(const u16x8*)(yraw + i);
    f32x4 q0 = ((const f32x4*)(res + i))[0];
    f32x4 q1 = ((const f32x4*)(res + i))[1];
    const float invN = 1.0f / (float)N_PTS;
    float ov[8];
    float m = 0.f;
#pragma unroll
    for (int j = 0; j < 8; ++j) {
        int c = c0 + j;
        float S = gpart[c], S2 = gpart[64 + c];
        float mu = S * invN;
        float var = S2 * invN - mu * mu;
        float s = gamma[c] * rsqrtf(var + 1e-4f);
        float r = (j < 4) ? q0[j] : q1[j - 4];
        ov[j] = fmaxf(bf2f(v[j]) * s + (beta[c] - mu * s) + r, 0.f);
        m = fmaxf(m, ov[j]);
    }
    m = fmaxf(m, __shfl_xor(m, 1));
    m = fmaxf(m, __shfl_xor(m, 2));
    m = fmaxf(m, __shfl_xor(m, 4));
    float inv = (m > 0.f) ? 127.0f / m : 0.f;
    i8x8 q;
#pragma unroll
    for (int j = 0; j < 8; ++j) q[j] = (char)(int)rintf(ov[j] * inv);
    *(i8x8*)(xq + i) = q;
    if ((t & 7) == 0) stbl[row] = m * (1.0f / 127.0f);
}

// ---------------- blk1: BN + int8-dequant residual + ReLU -> final f32 out ----------------
__global__ void bn_add_relu_final_k(const unsigned short* __restrict__ yraw,
                                    const float* __restrict__ gpart,
                                    const float* __restrict__ gamma,
                                    const float* __restrict__ beta,
                                    const char* __restrict__ resq,
                                    const float* __restrict__ res_stbl,
                                    float* __restrict__ xout) {
    int t = blockIdx.x * 256 + threadIdx.x;
    if (t >= TOTAL / 8) return;
    int i = t * 8;
    int row = t >> 3;
    int c0 = i & 63;
    u16x8 v = *(const u16x8*)(yraw + i);
    i8x8 rq = *(const i8x8*)(resq + i);
    float rs = res_stbl[row];
    const float invN = 1.0f / (float)N_PTS;
    f32x4 o0, o1;
#pragma unroll
    for (int j = 0; j < 8; ++j) {
        int c = c0 + j;
        float S = gpart[c], S2 = gpart[64 + c];
        float mu = S * invN;
        float var = S2 * invN - mu * mu;
        float s = gamma[c] * rsqrtf(var + 1e-4f);
        float r = (float)rq[j] * rs;
        float o = fmaxf(bf2f(v[j]) * s + (beta[c] - mu * s) + r, 0.f);
        if (j < 4) o0[j] = o; else o1[j - 4] = o;
    }
    ((f32x4*)(xout + i))[0] = o0;
    ((f32x4*)(xout + i))[1] = o1;
}

extern "C" void kernel_launch(void* const* d_in, const int* in_sizes, int n_in,
                              void* d_out, int out_size, void* d_ws, size_t ws_size,
                              hipStream_t stream) {
    const float* feats = (const float*)d_in[0];
    const int*   nbrs  = (const int*)d_in[1];
    const float* W     = (const float*)d_in[2];
    const float* gamma = (const float*)d_in[3];
    const float* beta  = (const float*)d_in[4];
    float* out = (float*)d_out;

    char* ws = (char*)d_ws;
    char*           xq0   = ws;                               //  6,400,128 B (incl pad row)
    float*          stbl0 = (float*)(ws + 6400128);           //    400,016 B
    char*           xq1   = ws + 6800144;                     //  6,400,128 B
    float*          stbl1 = (float*)(ws + 13200272);          //    400,016 B
    unsigned short* ybf   = (unsigned short*)(ws + 13600288); // 12,800,000 B
    unsigned short* Wp    = (unsigned short*)(ws + 26400288); //    917,504 B
    int*            nbrsT = (int*)(ws + 27317792);            // 11,210,752 B
    float*          gpart = (float*)(ws + 38528544);          //      2,048 B (4 slots x 128)

    dim3 b256(256);
    hipMemsetAsync(gpart, 0, 4 * 128 * sizeof(float), stream);
    const int qrows_blocks = ((N_PTS + 1) * 8 + 255) / 256;   // 3126
    cast_in_k<<<qrows_blocks, b256, 0, stream>>>(feats, xq0, stbl0);
    tr_nbrs_k<<<NT_STRIDE / 64, b256, 0, stream>>>(nbrs, nbrsT);
    pack_w_k<<<(4 * NKP * 4096) / 256, b256, 0, stream>>>(W, Wp);

    const int appl_blocks = (TOTAL / 8 + 255) / 256;          // 3125
    for (int blk = 0; blk < 2; ++blk) {
        const int c0 = blk * 2, c1 = blk * 2 + 1;
        // conv c0: xq0 -> ybf, stats -> slot c0
        conv_k<<<NB_CONV, b256, 0, stream>>>(
            xq0, stbl0, nbrsT, Wp + (size_t)c0 * NKP * 4096, ybf, gpart + c0 * 128);
        // bn(c0)+relu -> int8 xq1
        bn_relu_quant_k<<<qrows_blocks, b256, 0, stream>>>(
            ybf, gpart + c0 * 128, gamma + c0 * 64, beta + c0 * 64, xq1, stbl1);
        // conv c1: xq1 -> ybf, stats -> slot c1
        conv_k<<<NB_CONV, b256, 0, stream>>>(
            xq1, stbl1, nbrsT, Wp + (size_t)c1 * NKP * 4096, ybf, gpart + c1 * 128);
        if (blk == 0) {
            // bn(c1) + feats residual + relu -> int8 xq0 (conv3 input AND blk1 residual)
            bn_add_relu_quant_k<<<appl_blocks, b256, 0, stream>>>(
                ybf, gpart + c1 * 128, gamma + c1 * 64, beta + c1 * 64, feats, xq0, stbl0);
        } else {
            // bn(c1) + dequant(xq0) residual + relu -> final f32 out
            bn_add_relu_final_k<<<appl_blocks, b256, 0, stream>>>(
                ybf, gpart + c1 * 128, gamma + c1 * 64, beta + c1 * 64, xq0, stbl0, out);
        }
    }
}